// Round 20
// baseline (141.821 us; speedup 1.0000x reference)
//
#include <hip/hip_runtime.h>
#include <hip/hip_bf16.h>
#include <stdint.h>

#define B_ 8
#define N_ 1024
#define C_ 1024
#define H_ 16

static constexpr float SCALE = 0.125f;            // 64^-0.5
static constexpr float LOG2E = 1.4426950408889634f;
static constexpr float SL    = SCALE * LOG2E;     // folded into Wq at cvt time

typedef __attribute__((ext_vector_type(4))) float f32x4;
typedef __attribute__((ext_vector_type(8))) short s16x8;

__device__ __forceinline__ ushort f2bf(float f) {
    union { float f; uint32_t u; } c; c.f = f;
    uint32_t u = c.u;
    return (ushort)((u + 0x7fffu + ((u >> 16) & 1u)) >> 16);
}

// compiler-friendly cast: hipcc fuses pairs into v_cvt_pk_bf16_f32 (m240)
__device__ __forceinline__ ushort f2bfc(float f) {
    union { __hip_bfloat16 h; ushort u; } c;
    c.h = __float2bfloat16(f);
    return c.u;
}

__device__ __forceinline__ void gload_lds16(const void* g, void* l) {
    __builtin_amdgcn_global_load_lds(
        (const __attribute__((address_space(1))) void*)g,
        (__attribute__((address_space(3))) void*)l,
        16, 0, 0);
}
__device__ __forceinline__ void gload_lds4(const void* g, void* l) {
    __builtin_amdgcn_global_load_lds(
        (const __attribute__((address_space(1))) void*)g,
        (__attribute__((address_space(3))) void*)l,
        4, 0, 0);
}

// ---------------- fused fp32 -> bf16 conversion for all three inputs ----------------
__global__ __launch_bounds__(256) void cvt_all(const float* __restrict__ x,
                                               const float* __restrict__ qkv_w,
                                               const float* __restrict__ proj_w,
                                               ushort* __restrict__ xb,
                                               ushort* __restrict__ wqkv,
                                               ushort* __restrict__ wproj) {
    int i = blockIdx.x * 256 + threadIdx.x;
    const float* src;
    ushort* dst;
    float sc = 1.0f;
    if (i < 2097152) {
        src = x; dst = xb;
    } else if (i < 2097152 + 786432) {
        i -= 2097152;
        src = qkv_w; dst = wqkv;
        if (i < 262144) sc = SL;
    } else {
        i -= 2097152 + 786432;
        src = proj_w; dst = wproj;
    }
    float4 v = ((const float4*)src)[i];
    ushort4 o = make_ushort4(f2bf(v.x * sc), f2bf(v.y * sc), f2bf(v.z * sc), f2bf(v.w * sc));
    ((ushort4*)dst)[i] = o;
}

// ---------------- 128x128 m97-structure GEMM: C = A * B^T (+T1 XCD swizzle) ----------------
template<int OUT_BF16>
__global__ __launch_bounds__(256) void gemm_bt(const ushort* __restrict__ A,
                                               const ushort* __restrict__ Bw,
                                               void* __restrict__ Cout,
                                               const float* __restrict__ bias,
                                               int M, int Nout, int K) {
    __shared__ ushort Asm[128 * 64];
    __shared__ ushort Bsm[128 * 64];
    const int t = threadIdx.x;
    const int l = t & 63, w = t >> 6;
    const int lq = l & 15, lg = l >> 4;

    int bid = blockIdx.y * gridDim.x + blockIdx.x;
    const int cpx = (gridDim.x * gridDim.y) >> 3;
    bid = (bid & 7) * cpx + (bid >> 3);
    const int trow = (bid / gridDim.x) * 128, tcol = (bid % gridDim.x) * 128;

    const int wrow = (w >> 1) * 64, wcol = (w & 1) * 64;

    f32x4 acc[4][4] = {};

    const int srow0 = t >> 3;
    const int sc8 = (((t & 7) ^ (srow0 & 7)) * 8);
    const size_t abase = (size_t)(trow + srow0) * K + sc8;
    const size_t bbase = (size_t)(tcol + srow0) * K + sc8;

    for (int k0 = 0; k0 < K; k0 += 64) {
#pragma unroll
        for (int i = 0; i < 4; ++i) {
            gload_lds16(A + abase + (size_t)i * 32 * K + k0, &Asm[(i * 256 + w * 64) * 8]);
            gload_lds16(Bw + bbase + (size_t)i * 32 * K + k0, &Bsm[(i * 256 + w * 64) * 8]);
        }
        __syncthreads();
#pragma unroll
        for (int kk = 0; kk < 2; ++kk) {
            s16x8 af[4], bf[4];
#pragma unroll
            for (int m = 0; m < 4; ++m) {
                int row = wrow + m * 16 + lq;
                int ch = (kk * 4 + lg) ^ (row & 7);
                af[m] = *(const s16x8*)&Asm[row * 64 + ch * 8];
            }
#pragma unroll
            for (int n = 0; n < 4; ++n) {
                int row = wcol + n * 16 + lq;
                int ch = (kk * 4 + lg) ^ (row & 7);
                bf[n] = *(const s16x8*)&Bsm[row * 64 + ch * 8];
            }
#pragma unroll
            for (int m = 0; m < 4; ++m)
#pragma unroll
                for (int n = 0; n < 4; ++n)
                    acc[m][n] = __builtin_amdgcn_mfma_f32_16x16x32_bf16(af[m], bf[n], acc[m][n], 0, 0, 0);
        }
        __syncthreads();
    }

#pragma unroll
    for (int m = 0; m < 4; ++m)
#pragma unroll
        for (int n = 0; n < 4; ++n)
#pragma unroll
            for (int r = 0; r < 4; ++r) {
                int row = trow + wrow + m * 16 + lg * 4 + r;
                int col = tcol + wcol + n * 16 + lq;
                if (OUT_BF16) {
                    ((ushort*)Cout)[(size_t)row * Nout + col] = f2bfc(acc[m][n][r]);
                } else {
                    ((float*)Cout)[(size_t)row * Nout + col] = acc[m][n][r] + bias[col];
                }
            }
}

// ---------------- QK GEMM: 128x256 tile, single-buffer, 2 blocks/CU ----------------
// Inter-block TLP hides the per-tile stage drain (r19: dropped out of top-5, < attn).
__global__ __launch_bounds__(512, 4) void gemm_qk(const ushort* __restrict__ A,
                                                  const ushort* __restrict__ Bw,
                                                  ushort* __restrict__ Cout,
                                                  int M, int Nout, int K) {
    __shared__ ushort Asm[128 * 64];
    __shared__ ushort Bsm[256 * 64];
    const int t = threadIdx.x;
    const int l = t & 63, w = t >> 6;
    const int lq = l & 15, lg = l >> 4;
    const int wm = w >> 2, wn = w & 3;     // 2M x 4N waves, 64x64 out each

    int bid = blockIdx.y * gridDim.x + blockIdx.x;
    const int cpx = (gridDim.x * gridDim.y) >> 3;
    bid = (bid & 7) * cpx + (bid >> 3);
    const int bx = bid % gridDim.x, by = bid / gridDim.x;
    const int trow = by * 128, tcol = bx * 256;

    f32x4 acc[4][4] = {};

    const int srow0 = t >> 3;
    const int sc8 = ((t & 7) ^ (srow0 & 7)) * 8;
    const size_t abase = (size_t)(trow + srow0) * K + sc8;
    const size_t bbase = (size_t)(tcol + srow0) * K + sc8;

    for (int k0 = 0; k0 < K; k0 += 64) {
#pragma unroll
        for (int i = 0; i < 2; ++i)
            gload_lds16(A + abase + (size_t)i * 64 * K + k0, &Asm[(i * 512 + t) * 8]);
#pragma unroll
        for (int i = 0; i < 4; ++i)
            gload_lds16(Bw + bbase + (size_t)i * 64 * K + k0, &Bsm[(i * 512 + t) * 8]);
        __syncthreads();
#pragma unroll
        for (int kk = 0; kk < 2; ++kk) {
            s16x8 af[4], bf[4];
#pragma unroll
            for (int m = 0; m < 4; ++m) {
                int row = wm * 64 + m * 16 + lq;
                int ch = (kk * 4 + lg) ^ (row & 7);
                af[m] = *(const s16x8*)&Asm[row * 64 + ch * 8];
            }
#pragma unroll
            for (int n = 0; n < 4; ++n) {
                int row = wn * 64 + n * 16 + lq;
                int ch = (kk * 4 + lg) ^ (row & 7);
                bf[n] = *(const s16x8*)&Bsm[row * 64 + ch * 8];
            }
#pragma unroll
            for (int m = 0; m < 4; ++m)
#pragma unroll
                for (int n = 0; n < 4; ++n)
                    acc[m][n] = __builtin_amdgcn_mfma_f32_16x16x32_bf16(af[m], bf[n], acc[m][n], 0, 0, 0);
        }
        __syncthreads();
    }

#pragma unroll
    for (int m = 0; m < 4; ++m)
#pragma unroll
        for (int n = 0; n < 4; ++n)
#pragma unroll
            for (int r = 0; r < 4; ++r) {
                int row = trow + wm * 64 + m * 16 + lg * 4 + r;
                int col = tcol + wn * 64 + n * 16 + lq;
                Cout[(size_t)row * Nout + col] = f2bfc(acc[m][n][r]);
            }
}

// ---------------- fused flash attention: QBLK=256, KVBLK=64, K/V DOUBLE-BUFFER ----------------
// r19: attn is the top dispatch (47us) with ~38% stall; per tile the stage->barrier pattern
// eats full load latency serially, and at 2 blocks/CU there's little other-block TLP (r5's
// dbuf-null was at ~8 blocks/CU - different regime). dbuf: stage kt+1 BEFORE computing kt,
// ONE barrier/tile (was 2); the end-of-tile barrier drains kt+1's DMAs after ~500cyc of
// compute cover. Race audit: buffer p overwritten at kt+2's stage, issued only after the
// end-of-kt+1 barrier that retired all reads; DMA writes drain at each barrier.
__global__ __launch_bounds__(512, 4) void attn_fwd(const ushort* __restrict__ qk,
                                                   const ushort* __restrict__ vt,
                                                   ushort* __restrict__ attn_out) {
    __shared__ ushort Klds[2][64 * 64];
    __shared__ ushort Vlds[2][64 * 64];

    const int t = threadIdx.x, l = t & 63, w = t >> 6;
    const int lq = l & 15, lg = l >> 4;

    const int serial = blockIdx.x + 4 * blockIdx.y;
    const int logical = (serial & 7) * 64 + (serial >> 3);
    const int qt = logical & 3;
    const int bh = logical >> 2;
    const int b = bh >> 4, h = bh & 15;

    const int qbase = qt * 256 + w * 32 + lq;
    const size_t qoff0 = (size_t)(b * N_ + qbase) * 2048 + h * 64;
    const size_t qoff1 = qoff0 + (size_t)16 * 2048;
    const s16x8 qa0 = *(const s16x8*)&qk[qoff0 + lg * 8];
    const s16x8 qa1 = *(const s16x8*)&qk[qoff0 + 32 + lg * 8];
    const s16x8 qb0 = *(const s16x8*)&qk[qoff1 + lg * 8];
    const s16x8 qb1 = *(const s16x8*)&qk[qoff1 + 32 + lg * 8];

    float lr0 = 0.f, lr1 = 0.f;
    f32x4 o0[4] = {}, o1[4] = {};

    const int srow0 = t >> 3;
    const int sc8 = ((t & 7) ^ (srow0 & 7)) * 8;
    const size_t kgbase = (size_t)(b * N_ + srow0) * 2048 + 1024 + h * 64 + sc8;

    const ushort* vptr[4];
#pragma unroll
    for (int j = 0; j < 4; ++j) {
        const int d = 8 * w + 2 * j + (l >> 5);
        const int c = ((l & 31) >> 2) ^ (d & 7);
        const int s = c * 8 + (l & 3) * 2;
        const int key = (s >> 5) * 32 + ((s >> 2) & 1) * 16 + ((s >> 3) & 3) * 4 + (s & 3);
        vptr[j] = vt + (size_t)(h * 64 + d) * (B_ * N_) + b * N_ + key;
    }

#define STAGE_ATTN(buf, kt)                                                    \
    {                                                                          \
        gload_lds16(qk + kgbase + (size_t)(kt) * 64 * 2048, &Klds[buf][w * 512]); \
        _Pragma("unroll")                                                      \
        for (int j = 0; j < 4; ++j)                                            \
            gload_lds4(vptr[j] + (kt) * 64, &Vlds[buf][w * 512 + j * 128]);    \
    }

    // prologue: stage tile 0
    STAGE_ATTN(0, 0);
    __syncthreads();

    const int NT = N_ / 64;
    for (int kt = 0; kt < NT; ++kt) {
        const int cur = kt & 1, nxt = cur ^ 1;
        if (kt + 1 < NT) STAGE_ATTN(nxt, kt + 1);   // issue early; lands under compute

        f32x4 s0[4], s1[4];
#pragma unroll
        for (int g = 0; g < 4; ++g) {
            int key = g * 16 + lq;
            const s16x8 kf0 = *(const s16x8*)&Klds[cur][key * 64 + ((lg ^ (key & 7)) * 8)];
            const s16x8 kf1 = *(const s16x8*)&Klds[cur][key * 64 + (((4 + lg) ^ (key & 7)) * 8)];
            f32x4 z0 = {}, z1 = {};
            z0    = __builtin_amdgcn_mfma_f32_16x16x32_bf16(kf0, qa0, z0, 0, 0, 0);
            s0[g] = __builtin_amdgcn_mfma_f32_16x16x32_bf16(kf1, qa1, z0, 0, 0, 0);
            z1    = __builtin_amdgcn_mfma_f32_16x16x32_bf16(kf0, qb0, z1, 0, 0, 0);
            s1[g] = __builtin_amdgcn_mfma_f32_16x16x32_bf16(kf1, qb1, z1, 0, 0, 0);
        }

#pragma unroll
        for (int kb = 0; kb < 2; ++kb) {
            s16x8 pf0, pf1;
#pragma unroll
            for (int i = 0; i < 4; ++i) {
                float a0 = __builtin_amdgcn_exp2f(s0[2 * kb][i]);
                float a1 = __builtin_amdgcn_exp2f(s0[2 * kb + 1][i]);
                float b0 = __builtin_amdgcn_exp2f(s1[2 * kb][i]);
                float b1 = __builtin_amdgcn_exp2f(s1[2 * kb + 1][i]);
                lr0 += a0 + a1;
                lr1 += b0 + b1;
                pf0[i] = (short)f2bfc(a0); pf0[4 + i] = (short)f2bfc(a1);
                pf1[i] = (short)f2bfc(b0); pf1[4 + i] = (short)f2bfc(b1);
            }
#pragma unroll
            for (int ds = 0; ds < 4; ++ds) {
                const s16x8 vf = *(const s16x8*)
                    &Vlds[cur][(ds * 16 + lq) * 64 + (((kb * 4 + lg) ^ (lq & 7)) * 8)];
                o0[ds] = __builtin_amdgcn_mfma_f32_16x16x32_bf16(pf0, vf, o0[ds], 0, 0, 0);
                o1[ds] = __builtin_amdgcn_mfma_f32_16x16x32_bf16(pf1, vf, o1[ds], 0, 0, 0);
            }
        }
        __syncthreads();   // retires reads of cur; drains nxt's DMAs (issued ~500cyc ago)
    }
#undef STAGE_ATTN

    lr0 += __shfl_xor(lr0, 16); lr0 += __shfl_xor(lr0, 32);
    lr1 += __shfl_xor(lr1, 16); lr1 += __shfl_xor(lr1, 32);

#pragma unroll
    for (int r = 0; r < 4; ++r) {
        float rl0 = 1.f / __shfl(lr0, lg * 4 + r);
        float rl1 = 1.f / __shfl(lr1, lg * 4 + r);
        int orow = qt * 256 + w * 32 + lg * 4 + r;
        size_t base0 = (size_t)(b * N_ + orow) * C_ + h * 64 + lq;
        size_t base1 = base0 + (size_t)16 * C_;
#pragma unroll
        for (int ds = 0; ds < 4; ++ds) {
            attn_out[base0 + ds * 16] = f2bfc(o0[ds][r] * rl0);
            attn_out[base1 + ds * 16] = f2bfc(o1[ds][r] * rl1);
        }
    }
}

extern "C" void kernel_launch(void* const* d_in, const int* in_sizes, int n_in,
                              void* d_out, int out_size, void* d_ws, size_t ws_size,
                              hipStream_t stream) {
    const float* x      = (const float*)d_in[0];
    const float* qkv_w  = (const float*)d_in[1];
    const float* proj_w = (const float*)d_in[2];
    const float* proj_b = (const float*)d_in[3];
    float* out = (float*)d_out;

    ushort* ws    = (ushort*)d_ws;
    ushort* xb    = ws;                                   //  8192*1024
    ushort* wqkv  = xb + (size_t)8192 * 1024;             //  3072*1024
    ushort* wproj = wqkv + (size_t)3072 * 1024;           //  1024*1024
    ushort* qkb   = wproj + (size_t)1024 * 1024;          //  8192*2048
    ushort* vtb   = qkb + (size_t)8192 * 2048;            //  1024*8192
    ushort* attn  = vtb + (size_t)1024 * 8192;            //  8192*1024

    cvt_all<<<12288, 256, 0, stream>>>(x, qkv_w, proj_w, xb, wqkv, wproj);

    // Q,K: [token][2048] via 128x256 single-buffer (2 blocks/CU -> inter-block TLP)
    gemm_qk<<<dim3(8, 64), 512, 0, stream>>>(xb, wqkv, qkb, 8192, 2048, 1024);
    // V^T: [c][token]
    gemm_bt<1><<<dim3(64, 8), 256, 0, stream>>>(wqkv + (size_t)2048 * 1024, xb, (void*)vtb,
                                                nullptr, 1024, 8192, 1024);

    attn_fwd<<<dim3(4, 128), 512, 0, stream>>>(qkb, vtb, attn);

    gemm_bt<0><<<dim3(8, 64), 256, 0, stream>>>(attn, wproj, (void*)out, proj_b, 8192, 1024, 1024);
}

// Round 21
// 139.625 us; speedup vs baseline: 1.0157x; 1.0157x over previous
//
#include <hip/hip_runtime.h>
#include <hip/hip_bf16.h>
#include <stdint.h>

#define B_ 8
#define N_ 1024
#define C_ 1024
#define H_ 16

static constexpr float SCALE = 0.125f;            // 64^-0.5
static constexpr float LOG2E = 1.4426950408889634f;
static constexpr float SL    = SCALE * LOG2E;     // folded into Wq at cvt time

typedef __attribute__((ext_vector_type(4))) float f32x4;
typedef __attribute__((ext_vector_type(8))) short s16x8;

__device__ __forceinline__ ushort f2bf(float f) {
    union { float f; uint32_t u; } c; c.f = f;
    uint32_t u = c.u;
    return (ushort)((u + 0x7fffu + ((u >> 16) & 1u)) >> 16);
}

// compiler-friendly cast: hipcc fuses pairs into v_cvt_pk_bf16_f32 (m240)
__device__ __forceinline__ ushort f2bfc(float f) {
    union { __hip_bfloat16 h; ushort u; } c;
    c.h = __float2bfloat16(f);
    return c.u;
}

__device__ __forceinline__ void gload_lds16(const void* g, void* l) {
    __builtin_amdgcn_global_load_lds(
        (const __attribute__((address_space(1))) void*)g,
        (__attribute__((address_space(3))) void*)l,
        16, 0, 0);
}
__device__ __forceinline__ void gload_lds4(const void* g, void* l) {
    __builtin_amdgcn_global_load_lds(
        (const __attribute__((address_space(1))) void*)g,
        (__attribute__((address_space(3))) void*)l,
        4, 0, 0);
}

// ---------------- fused fp32 -> bf16 conversion for all three inputs ----------------
__global__ __launch_bounds__(256) void cvt_all(const float* __restrict__ x,
                                               const float* __restrict__ qkv_w,
                                               const float* __restrict__ proj_w,
                                               ushort* __restrict__ xb,
                                               ushort* __restrict__ wqkv,
                                               ushort* __restrict__ wproj) {
    int i = blockIdx.x * 256 + threadIdx.x;
    const float* src;
    ushort* dst;
    float sc = 1.0f;
    if (i < 2097152) {
        src = x; dst = xb;
    } else if (i < 2097152 + 786432) {
        i -= 2097152;
        src = qkv_w; dst = wqkv;
        if (i < 262144) sc = SL;
    } else {
        i -= 2097152 + 786432;
        src = proj_w; dst = wproj;
    }
    float4 v = ((const float4*)src)[i];
    ushort4 o = make_ushort4(f2bf(v.x * sc), f2bf(v.y * sc), f2bf(v.z * sc), f2bf(v.w * sc));
    ((ushort4*)dst)[i] = o;
}

// ---------------- 128x128 m97-structure GEMM: C = A * B^T (+T1 XCD swizzle) ----------------
template<int OUT_BF16>
__global__ __launch_bounds__(256) void gemm_bt(const ushort* __restrict__ A,
                                               const ushort* __restrict__ Bw,
                                               void* __restrict__ Cout,
                                               const float* __restrict__ bias,
                                               int M, int Nout, int K) {
    __shared__ ushort Asm[128 * 64];
    __shared__ ushort Bsm[128 * 64];
    const int t = threadIdx.x;
    const int l = t & 63, w = t >> 6;
    const int lq = l & 15, lg = l >> 4;

    int bid = blockIdx.y * gridDim.x + blockIdx.x;
    const int cpx = (gridDim.x * gridDim.y) >> 3;
    bid = (bid & 7) * cpx + (bid >> 3);
    const int trow = (bid / gridDim.x) * 128, tcol = (bid % gridDim.x) * 128;

    const int wrow = (w >> 1) * 64, wcol = (w & 1) * 64;

    f32x4 acc[4][4] = {};

    const int srow0 = t >> 3;
    const int sc8 = (((t & 7) ^ (srow0 & 7)) * 8);
    const size_t abase = (size_t)(trow + srow0) * K + sc8;
    const size_t bbase = (size_t)(tcol + srow0) * K + sc8;

    for (int k0 = 0; k0 < K; k0 += 64) {
#pragma unroll
        for (int i = 0; i < 4; ++i) {
            gload_lds16(A + abase + (size_t)i * 32 * K + k0, &Asm[(i * 256 + w * 64) * 8]);
            gload_lds16(Bw + bbase + (size_t)i * 32 * K + k0, &Bsm[(i * 256 + w * 64) * 8]);
        }
        __syncthreads();
#pragma unroll
        for (int kk = 0; kk < 2; ++kk) {
            s16x8 af[4], bf[4];
#pragma unroll
            for (int m = 0; m < 4; ++m) {
                int row = wrow + m * 16 + lq;
                int ch = (kk * 4 + lg) ^ (row & 7);
                af[m] = *(const s16x8*)&Asm[row * 64 + ch * 8];
            }
#pragma unroll
            for (int n = 0; n < 4; ++n) {
                int row = wcol + n * 16 + lq;
                int ch = (kk * 4 + lg) ^ (row & 7);
                bf[n] = *(const s16x8*)&Bsm[row * 64 + ch * 8];
            }
#pragma unroll
            for (int m = 0; m < 4; ++m)
#pragma unroll
                for (int n = 0; n < 4; ++n)
                    acc[m][n] = __builtin_amdgcn_mfma_f32_16x16x32_bf16(af[m], bf[n], acc[m][n], 0, 0, 0);
        }
        __syncthreads();
    }

#pragma unroll
    for (int m = 0; m < 4; ++m)
#pragma unroll
        for (int n = 0; n < 4; ++n)
#pragma unroll
            for (int r = 0; r < 4; ++r) {
                int row = trow + wrow + m * 16 + lg * 4 + r;
                int col = tcol + wcol + n * 16 + lq;
                if (OUT_BF16) {
                    ((ushort*)Cout)[(size_t)row * Nout + col] = f2bfc(acc[m][n][r]);
                } else {
                    ((float*)Cout)[(size_t)row * Nout + col] = acc[m][n][r] + bias[col];
                }
            }
}

// ---------------- QK GEMM: 128x256 tile, single-buffer, 2 blocks/CU ----------------
// Inter-block TLP hides the per-tile stage drain (r19: dropped out of top-5, < attn).
__global__ __launch_bounds__(512, 4) void gemm_qk(const ushort* __restrict__ A,
                                                  const ushort* __restrict__ Bw,
                                                  ushort* __restrict__ Cout,
                                                  int M, int Nout, int K) {
    __shared__ ushort Asm[128 * 64];
    __shared__ ushort Bsm[256 * 64];
    const int t = threadIdx.x;
    const int l = t & 63, w = t >> 6;
    const int lq = l & 15, lg = l >> 4;
    const int wm = w >> 2, wn = w & 3;     // 2M x 4N waves, 64x64 out each

    int bid = blockIdx.y * gridDim.x + blockIdx.x;
    const int cpx = (gridDim.x * gridDim.y) >> 3;
    bid = (bid & 7) * cpx + (bid >> 3);
    const int bx = bid % gridDim.x, by = bid / gridDim.x;
    const int trow = by * 128, tcol = bx * 256;

    f32x4 acc[4][4] = {};

    const int srow0 = t >> 3;
    const int sc8 = ((t & 7) ^ (srow0 & 7)) * 8;
    const size_t abase = (size_t)(trow + srow0) * K + sc8;
    const size_t bbase = (size_t)(tcol + srow0) * K + sc8;

    for (int k0 = 0; k0 < K; k0 += 64) {
#pragma unroll
        for (int i = 0; i < 2; ++i)
            gload_lds16(A + abase + (size_t)i * 64 * K + k0, &Asm[(i * 512 + t) * 8]);
#pragma unroll
        for (int i = 0; i < 4; ++i)
            gload_lds16(Bw + bbase + (size_t)i * 64 * K + k0, &Bsm[(i * 512 + t) * 8]);
        __syncthreads();
#pragma unroll
        for (int kk = 0; kk < 2; ++kk) {
            s16x8 af[4], bf[4];
#pragma unroll
            for (int m = 0; m < 4; ++m) {
                int row = wm * 64 + m * 16 + lq;
                int ch = (kk * 4 + lg) ^ (row & 7);
                af[m] = *(const s16x8*)&Asm[row * 64 + ch * 8];
            }
#pragma unroll
            for (int n = 0; n < 4; ++n) {
                int row = wn * 64 + n * 16 + lq;
                int ch = (kk * 4 + lg) ^ (row & 7);
                bf[n] = *(const s16x8*)&Bsm[row * 64 + ch * 8];
            }
#pragma unroll
            for (int m = 0; m < 4; ++m)
#pragma unroll
                for (int n = 0; n < 4; ++n)
                    acc[m][n] = __builtin_amdgcn_mfma_f32_16x16x32_bf16(af[m], bf[n], acc[m][n], 0, 0, 0);
        }
        __syncthreads();
    }

#pragma unroll
    for (int m = 0; m < 4; ++m)
#pragma unroll
        for (int n = 0; n < 4; ++n)
#pragma unroll
            for (int r = 0; r < 4; ++r) {
                int row = trow + wm * 64 + m * 16 + lg * 4 + r;
                int col = tcol + wn * 64 + n * 16 + lq;
                Cout[(size_t)row * Nout + col] = f2bfc(acc[m][n][r]);
            }
}

// ---------------- fused flash attention (QBLK=256, KVBLK=64, single-buffer -- r19 exact) ----
// Measured optimum. Ledger: QBLK {64:67, 128:61, 256:47, 512:53}us; KVBLK=128 rejected twice
// (r10/r14: 96us, 159MB FETCH); K/V dbuf rejected twice (r5 +1us, r20 +2us) -- staging
// pipelines don't pay at HIP source on this chip (guide m131-m141 concurs).
__global__ __launch_bounds__(512, 4) void attn_fwd(const ushort* __restrict__ qk,
                                                   const ushort* __restrict__ vt,
                                                   ushort* __restrict__ attn_out) {
    __shared__ ushort Klds[64 * 64];
    __shared__ ushort Vlds[64 * 64];

    const int t = threadIdx.x, l = t & 63, w = t >> 6;
    const int lq = l & 15, lg = l >> 4;

    const int serial = blockIdx.x + 4 * blockIdx.y;
    const int logical = (serial & 7) * 64 + (serial >> 3);
    const int qt = logical & 3;
    const int bh = logical >> 2;
    const int b = bh >> 4, h = bh & 15;

    const int qbase = qt * 256 + w * 32 + lq;
    const size_t qoff0 = (size_t)(b * N_ + qbase) * 2048 + h * 64;
    const size_t qoff1 = qoff0 + (size_t)16 * 2048;
    const s16x8 qa0 = *(const s16x8*)&qk[qoff0 + lg * 8];
    const s16x8 qa1 = *(const s16x8*)&qk[qoff0 + 32 + lg * 8];
    const s16x8 qb0 = *(const s16x8*)&qk[qoff1 + lg * 8];
    const s16x8 qb1 = *(const s16x8*)&qk[qoff1 + 32 + lg * 8];

    float lr0 = 0.f, lr1 = 0.f;
    f32x4 o0[4] = {}, o1[4] = {};

    const int srow0 = t >> 3;
    const int sc8 = ((t & 7) ^ (srow0 & 7)) * 8;
    const size_t kgbase = (size_t)(b * N_ + srow0) * 2048 + 1024 + h * 64 + sc8;

    const ushort* vptr[4];
#pragma unroll
    for (int j = 0; j < 4; ++j) {
        const int d = 8 * w + 2 * j + (l >> 5);
        const int c = ((l & 31) >> 2) ^ (d & 7);
        const int s = c * 8 + (l & 3) * 2;
        const int key = (s >> 5) * 32 + ((s >> 2) & 1) * 16 + ((s >> 3) & 3) * 4 + (s & 3);
        vptr[j] = vt + (size_t)(h * 64 + d) * (B_ * N_) + b * N_ + key;
    }

    for (int kt = 0; kt < N_ / 64; ++kt) {
        gload_lds16(qk + kgbase + (size_t)kt * 64 * 2048, &Klds[w * 512]);
#pragma unroll
        for (int j = 0; j < 4; ++j)
            gload_lds4(vptr[j] + kt * 64, &Vlds[w * 512 + j * 128]);
        __syncthreads();

        f32x4 s0[4], s1[4];
#pragma unroll
        for (int g = 0; g < 4; ++g) {
            int key = g * 16 + lq;
            const s16x8 kf0 = *(const s16x8*)&Klds[key * 64 + ((lg ^ (key & 7)) * 8)];
            const s16x8 kf1 = *(const s16x8*)&Klds[key * 64 + (((4 + lg) ^ (key & 7)) * 8)];
            f32x4 z0 = {}, z1 = {};
            z0    = __builtin_amdgcn_mfma_f32_16x16x32_bf16(kf0, qa0, z0, 0, 0, 0);
            s0[g] = __builtin_amdgcn_mfma_f32_16x16x32_bf16(kf1, qa1, z0, 0, 0, 0);
            z1    = __builtin_amdgcn_mfma_f32_16x16x32_bf16(kf0, qb0, z1, 0, 0, 0);
            s1[g] = __builtin_amdgcn_mfma_f32_16x16x32_bf16(kf1, qb1, z1, 0, 0, 0);
        }

#pragma unroll
        for (int kb = 0; kb < 2; ++kb) {
            s16x8 pf0, pf1;
#pragma unroll
            for (int i = 0; i < 4; ++i) {
                float a0 = __builtin_amdgcn_exp2f(s0[2 * kb][i]);
                float a1 = __builtin_amdgcn_exp2f(s0[2 * kb + 1][i]);
                float b0 = __builtin_amdgcn_exp2f(s1[2 * kb][i]);
                float b1 = __builtin_amdgcn_exp2f(s1[2 * kb + 1][i]);
                lr0 += a0 + a1;
                lr1 += b0 + b1;
                pf0[i] = (short)f2bfc(a0); pf0[4 + i] = (short)f2bfc(a1);
                pf1[i] = (short)f2bfc(b0); pf1[4 + i] = (short)f2bfc(b1);
            }
#pragma unroll
            for (int ds = 0; ds < 4; ++ds) {
                const s16x8 vf = *(const s16x8*)
                    &Vlds[(ds * 16 + lq) * 64 + (((kb * 4 + lg) ^ (lq & 7)) * 8)];
                o0[ds] = __builtin_amdgcn_mfma_f32_16x16x32_bf16(pf0, vf, o0[ds], 0, 0, 0);
                o1[ds] = __builtin_amdgcn_mfma_f32_16x16x32_bf16(pf1, vf, o1[ds], 0, 0, 0);
            }
        }
        __syncthreads();
    }

    lr0 += __shfl_xor(lr0, 16); lr0 += __shfl_xor(lr0, 32);
    lr1 += __shfl_xor(lr1, 16); lr1 += __shfl_xor(lr1, 32);

#pragma unroll
    for (int r = 0; r < 4; ++r) {
        float rl0 = 1.f / __shfl(lr0, lg * 4 + r);
        float rl1 = 1.f / __shfl(lr1, lg * 4 + r);
        int orow = qt * 256 + w * 32 + lg * 4 + r;
        size_t base0 = (size_t)(b * N_ + orow) * C_ + h * 64 + lq;
        size_t base1 = base0 + (size_t)16 * C_;
#pragma unroll
        for (int ds = 0; ds < 4; ++ds) {
            attn_out[base0 + ds * 16] = f2bfc(o0[ds][r] * rl0);
            attn_out[base1 + ds * 16] = f2bfc(o1[ds][r] * rl1);
        }
    }
}

extern "C" void kernel_launch(void* const* d_in, const int* in_sizes, int n_in,
                              void* d_out, int out_size, void* d_ws, size_t ws_size,
                              hipStream_t stream) {
    const float* x      = (const float*)d_in[0];
    const float* qkv_w  = (const float*)d_in[1];
    const float* proj_w = (const float*)d_in[2];
    const float* proj_b = (const float*)d_in[3];
    float* out = (float*)d_out;

    ushort* ws    = (ushort*)d_ws;
    ushort* xb    = ws;                                   //  8192*1024
    ushort* wqkv  = xb + (size_t)8192 * 1024;             //  3072*1024
    ushort* wproj = wqkv + (size_t)3072 * 1024;           //  1024*1024
    ushort* qkb   = wproj + (size_t)1024 * 1024;          //  8192*2048
    ushort* vtb   = qkb + (size_t)8192 * 2048;            //  1024*8192
    ushort* attn  = vtb + (size_t)1024 * 8192;            //  8192*1024

    cvt_all<<<12288, 256, 0, stream>>>(x, qkv_w, proj_w, xb, wqkv, wproj);

    // Q,K: [token][2048] via 128x256 single-buffer (2 blocks/CU -> inter-block TLP)
    gemm_qk<<<dim3(8, 64), 512, 0, stream>>>(xb, wqkv, qkb, 8192, 2048, 1024);
    // V^T: [c][token]
    gemm_bt<1><<<dim3(64, 8), 256, 0, stream>>>(wqkv + (size_t)2048 * 1024, xb, (void*)vtb,
                                                nullptr, 1024, 8192, 1024);

    attn_fwd<<<dim3(4, 128), 512, 0, stream>>>(qkb, vtb, attn);

    gemm_bt<0><<<dim3(8, 64), 256, 0, stream>>>(attn, wproj, (void*)out, proj_b, 8192, 1024, 1024);
}